// Round 14
// baseline (66.861 us; speedup 1.0000x reference)
//
#include <hip/hip_runtime.h>

// CostVolume2D: B=8, H=256, W=512, C=32, n_disp=12, stride=1.
// cost[b,h,w,d] = sum_c |feat_l[b,h,w,c] - feat_r[b,h,w-d,c]|, feat_r zero-padded left.
//
// r14: cross-tile double-buffered pipeline. r7 (57.8us) ~= HBM(29) + LDS(31)
// SUMMED: its __syncthreads drained vmcnt(0) so stage and compute never overlap.
// Here each block runs NT=4 half-row tiles with 2 LDS buffers; stage(tt+1) is
// issued BEFORE a COUNTED s_waitcnt vmcnt(10) + raw s_barrier, so the next
// tile's 10 glld/wave stream from HBM underneath compute(tt). Never vmcnt(0)
// mid-loop (T3/T4 recipe).
//
// Components kept verbatim from r7 (all HW-verified there):
//   stage: wave w stages planes {2w,2w+1}, dest lane-linear, src col*128B+q*16B
//          -> compulsory FETCH; 10 glld/wave uniform -> exact vmcnt literals.
//   reads: plane-major NCOL=272, lane-consecutive, 1 base + 12 imm offsets
//          -> 0 bank conflicts.
// lsum/L first-use is AFTER the counted wait so the compiler's auto-waitcnt
// for the feat_l regs cannot serialize the stage issue.

constexpr int ND   = 12;
constexpr int NCOL = 272;              // chunks per plane (267 used)
constexpr int TCH  = 8 * NCOL;         // 2176 chunks per tile buffer (34816 B)
constexpr int NT   = 4;                // tiles (half-rows) per block

typedef float vfloat4 __attribute__((ext_vector_type(4)));

__device__ __forceinline__ float l1_4(float4 a, float4 b) {
    return fabsf(a.x - b.x) + fabsf(a.y - b.y) + fabsf(a.z - b.z) + fabsf(a.w - b.w);
}
__device__ __forceinline__ float abs4(float4 a) {
    return fabsf(a.x) + fabsf(a.y) + fabsf(a.z) + fabsf(a.w);
}

__device__ __forceinline__ void stage_tile(const float* __restrict__ fr, int tile,
                                           float4* dst, int wave, int lane)
{
    const int bh     = tile >> 1;
    const int wstart = (tile & 1) * 256;
    const float* fr_row = fr + (size_t)bh * 512 * 32;
    #pragma unroll
    for (int run = 0; run < 5; ++run) {
        const int colr = run * 64 + lane;
        int col = wstart - 11 + colr;
        col = max(col, 0);                         // guard cols clamped, never used
        if (run < 4 || lane < 11) {                // 267 cols; 10 glld per wave uniform
            #pragma unroll
            for (int dq = 0; dq < 2; ++dq) {
                const int q = 2 * wave + dq;
                __builtin_amdgcn_global_load_lds(
                    (const __attribute__((address_space(1))) void*)(fr_row + (size_t)col * 32 + q * 4),
                    (__attribute__((address_space(3))) void*)(dst + q * NCOL + colr),
                    16, 0, 0);
            }
        }
    }
}

__global__ __launch_bounds__(256) void cost_volume_kernel(
    const float* __restrict__ fl,
    const float* __restrict__ fr,
    float* __restrict__ out)
{
    __shared__ float4 lds4[2 * TCH];               // 69632 B -> 2 blocks/CU

    const int t    = threadIdx.x;
    const int wave = t >> 6;
    const int lane = t & 63;
    const int tile0 = blockIdx.x * NT;

    stage_tile(fr, tile0, lds4, wave, lane);       // prologue: fill buf0

    #pragma unroll 1
    for (int tt = 0; tt < NT; ++tt) {
        const int tile = tile0 + tt;
        const int bh   = tile >> 1;
        const int w    = (tile & 1) * 256 + t;
        const size_t pix = (size_t)bh * 512 + w;

        // ---- issue feat_l(tt) loads (values not touched until after the wait)
        const float4* lp = reinterpret_cast<const float4*>(fl) + pix * 8;
        float4 L[8];
        #pragma unroll
        for (int q = 0; q < 8; ++q) L[q] = lp[q];

        // ---- issue stage(tt+1) into the other buffer; stays in flight
        if (tt + 1 < NT)
            stage_tile(fr, tile + 1, lds4 + ((tt + 1) & 1) * TCH, wave, lane);

        // ---- counted wait: drain stage(tt)+feat_l(tt), keep stage(tt+1) in flight
        if (tt + 1 < NT) {
            asm volatile("s_waitcnt vmcnt(10)" ::: "memory");
        } else {
            asm volatile("s_waitcnt vmcnt(0)" ::: "memory");
        }
        __builtin_amdgcn_s_barrier();              // raw: no compiler vmcnt(0) drain

        // ---- compute(tt): r7's verified 0-conflict pattern
        const float4* buf = lds4 + (tt & 1) * TCH;
        float lsum = 0.f;
        float res[ND];
        #pragma unroll
        for (int d = 0; d < ND; ++d) res[d] = 0.f;

        #pragma unroll
        for (int q = 0; q < 8; ++q) {
            const float4 Lq = L[q];
            lsum += abs4(Lq);
            const float4* base = buf + q * NCOL + t;     // colr = t + (11-d)
            #pragma unroll
            for (int d = 0; d < ND; ++d)
                res[d] += l1_4(Lq, base[11 - d]);
        }

        // left edge: w < d -> feat_r fully shifted out (zeros) -> sum|feat_l|
        #pragma unroll
        for (int d = 0; d < ND; ++d)
            if (w < d) res[d] = lsum;

        vfloat4* op = reinterpret_cast<vfloat4*>(out + pix * ND);
        vfloat4 o0 = {res[0], res[1], res[2],  res[3]};
        vfloat4 o1 = {res[4], res[5], res[6],  res[7]};
        vfloat4 o2 = {res[8], res[9], res[10], res[11]};
        __builtin_nontemporal_store(o0, op + 0);
        __builtin_nontemporal_store(o1, op + 1);
        __builtin_nontemporal_store(o2, op + 2);

        __builtin_amdgcn_s_barrier();              // all reads of buf done before reuse
    }
}

extern "C" void kernel_launch(void* const* d_in, const int* in_sizes, int n_in,
                              void* d_out, int out_size, void* d_ws, size_t ws_size,
                              hipStream_t stream)
{
    const float* fl = (const float*)d_in[0];
    const float* fr = (const float*)d_in[1];
    float* out = (float*)d_out;

    const int grid = 8 * 256 * 2 / NT;             // 1024 blocks x 4 tiles
    cost_volume_kernel<<<grid, 256, 0, stream>>>(fl, fr, out);
}